// Round 5
// baseline (226.611 us; speedup 1.0000x reference)
//
#include <hip/hip_runtime.h>

// PPO model loss — R12: fused kernel + tree barrier with BROADCAST release.
// R11 measurement: fusion passed, FETCH ~50MB (re-read gone), but 88us @
// VALUBusy 6% — a ~70us near-idle stall. Cause: bar_wait had 512 waves
// spin-polling ONE agent-scope line; same-line coherence-point serialization
// (R8's ~20ns/op) makes each poll queue ~10us. WRITE_SIZE=116KB proved no
// scratch spill, so register retention is fine — the spin was the tail.
// R12 changes ONE thing: the releaser fans the flag out to 64 lines (128B
// apart); block b polls only line (b&63) -> <=8 pollers/line + s_sleep(8)
// backoff. Post-barrier data reads are plain loads (ordered by the acquire).
//
//   phase A: 2 rows/block, wave-scan + LDS-compose, row stats ->
//            per-block (s1,s2) doubles; RETAIN v[], L[], carry in registers.
//   bar1   : tree arrival (64 lines x8 -> 8 lines x8 -> 1) + 64-line release.
//   phase B: every block reduces the 512 (s1,s2) pairs -> mean/invstd; loss
//            from RETAINED state + fresh va/lp/ol/mk streams; partials.
//   bar2   : arrival only for blocks 1..511; block 0 waits, reduces 512
//            partial triples -> scalar loss.
//
// ws: [0)      2 barriers x 144 lines x 32 ints (128B stride)
//     [65536)  blkS1[512], blkS2[512], part[3*512] doubles

static constexpr int T_DIM = 4096;
static constexpr int SEG   = 512;          // elements per segment (one wave)
static constexpr int NSEG  = 8;            // segments per row
static constexpr int CH    = 8;            // elements per lane
static constexpr int BT    = 512;          // 8 waves per block
static constexpr int NW    = 8;
static constexpr int RPB   = 2;            // rows per block
static constexpr int NBLK  = 512;          // grid = nrows / RPB  (nrows=1024)

#define CDEC 0.95f
#define CLIPR 0.2f
#define CLIPV 0.2f
#define AGENT __HIP_MEMORY_SCOPE_AGENT

// ------- barrier state: 144 lines x 32 ints (counters 0..72, flags 80..143)
static constexpr int LSTRIDE  = 32;             // 128 B between lines
static constexpr int BAR_INTS = 144 * LSTRIDE;

__device__ __forceinline__ void bar_arrive(int* base, int bid) {
  // thread 0 of each block; caller's global stores must precede
  __threadfence();   // make prior agent stores visible before arrival
  const int line0 = bid & 63;
  if (__hip_atomic_fetch_add(base + line0 * LSTRIDE, 1,
                             __ATOMIC_ACQ_REL, AGENT) == (NBLK >> 6) - 1) {
    if (__hip_atomic_fetch_add(base + (64 + (line0 >> 3)) * LSTRIDE, 1,
                               __ATOMIC_ACQ_REL, AGENT) == 7) {
      if (__hip_atomic_fetch_add(base + 72 * LSTRIDE, 1,
                                 __ATOMIC_ACQ_REL, AGENT) == 7) {
        // broadcast release: 64 flag lines, <=8 pollers each
#pragma unroll
        for (int i = 0; i < 64; ++i)
          __hip_atomic_store(base + (80 + i) * LSTRIDE, 1,
                             __ATOMIC_RELEASE, AGENT);
      }
    }
  }
}
__device__ __forceinline__ void bar_wait(int* base, int bid) {
  int* flag = base + (80 + (bid & 63)) * LSTRIDE;
  while (__hip_atomic_load(flag, __ATOMIC_ACQUIRE, AGENT) == 0)
    __builtin_amdgcn_s_sleep(8);
}

__device__ __forceinline__ double wave_sum_d(double v) {
#pragma unroll
  for (int d = 32; d > 0; d >>= 1) v += __shfl_down(v, d);
  return v;
}
// inclusive suffix scan of affine (L, M) across the 64-lane wave
__device__ __forceinline__ void wave_suffix(float& sL, float& sM, int lane) {
#pragma unroll
  for (int d = 1; d < 64; d <<= 1) {
    float oL = __shfl_down(sL, d);
    float oM = __shfl_down(sM, d);
    if (lane + d < 64) { sL += sM * oL; sM *= oM; }
  }
}

// ---------------- init: zero barrier state ---------------------------------
__global__ __launch_bounds__(256) void init_kernel(int* bar) {
  for (int i = threadIdx.x; i < 2 * BAR_INTS; i += 256) bar[i] = 0;
}

// ---------------- fused kernel (plain launch, capacity-guaranteed) ---------
__global__ __launch_bounds__(BT, 4) void coop_kernel(
    const float* __restrict__ logprobs,
    const float* __restrict__ values,
    const float* __restrict__ old_logprobs,
    const float* __restrict__ old_values,
    const float* __restrict__ rewards,
    const int*   __restrict__ mask,
    int* __restrict__ bar1, int* __restrict__ bar2,
    double* __restrict__ blkS1, double* __restrict__ blkS2,
    double* __restrict__ part, float* __restrict__ out) {
  const int tid  = threadIdx.x;
  const int lane = tid & 63;
  const int seg  = tid >> 6;          // wave id == segment id within row
  const int bid  = blockIdx.x;
  const float c  = CDEC;

  __shared__ float  segL[NSEG], segM[NSEG], segC[NSEG];
  __shared__ double red2[2][NW];
  __shared__ double red3[3][NW];
  __shared__ float  sc[2];

  float cCH;
  { float pw = 1.f;
#pragma unroll
    for (int i = 0; i < CH; ++i) pw *= c;
    cCH = pw; }

  // ---------------- phase A: row stats, retain scan state ------------------
  float vK[RPB][CH], LK[RPB][CH], carryK[RPB];
  double s1d = 0.0, s2d = 0.0;

#pragma unroll
  for (int r = 0; r < RPB; ++r) {
    const int  row  = bid * RPB + r;
    const long base = ((long)row * NSEG + seg) * SEG + (long)lane * CH;

    const float4 rv0 = *(const float4*)(rewards + base);
    const float4 rv1 = *(const float4*)(rewards + base + 4);
    const float4 vv0 = *(const float4*)(old_values + base);
    const float4 vv1 = *(const float4*)(old_values + base + 4);

    float v9[CH + 1], rw[CH];
    v9[0] = vv0.x; v9[1] = vv0.y; v9[2] = vv0.z; v9[3] = vv0.w;
    v9[4] = vv1.x; v9[5] = vv1.y; v9[6] = vv1.z; v9[7] = vv1.w;
    rw[0] = rv0.x; rw[1] = rv0.y; rw[2] = rv0.z; rw[3] = rv0.w;
    rw[4] = rv1.x; rw[5] = rv1.y; rw[6] = rv1.z; rw[7] = rv1.w;
    float nv = __shfl_down(v9[0], 1);
    if (lane == 63) nv = (seg == NSEG - 1) ? 0.f : old_values[base + CH];
    v9[CH] = nv;

    // local suffix scan (zero carry-in)
    LK[r][CH - 1] = rw[CH - 1] + v9[CH] - v9[CH - 1];
#pragma unroll
    for (int j = CH - 2; j >= 0; --j)
      LK[r][j] = (rw[j] + v9[j + 1] - v9[j]) + c * LK[r][j + 1];
#pragma unroll
    for (int j = 0; j < CH; ++j) vK[r][j] = v9[j];

    float sL = LK[r][0], sM = cCH;
    wave_suffix(sL, sM, lane);
    float nLc = __shfl_down(sL, 1);
    float nMc = __shfl_down(sM, 1);
    if (lane == 63) { nLc = 0.f; nMc = 1.f; }

    if (lane == 0) { segL[seg] = sL; segM[seg] = sM; }
    __syncthreads();
    if (tid == 0) {
      float C = 0.f;
#pragma unroll
      for (int s = NSEG - 1; s >= 0; --s) { segC[s] = C; C = segL[s] + segM[s] * C; }
    }
    __syncthreads();
    carryK[r] = nLc + nMc * segC[seg];

    float s1 = 0.f, s2 = 0.f;
    { float cpw = 1.f;
#pragma unroll
      for (int j = CH - 1; j >= 0; --j) {
        cpw *= c;                        // c^(CH-j)
        const float A = LK[r][j] + carryK[r] * cpw;
        s1 += A; s2 += A * A;
      } }

    double d1 = wave_sum_d((double)s1);
    double d2 = wave_sum_d((double)s2);
    if (lane == 0) { red2[0][seg] = d1; red2[1][seg] = d2; }
    __syncthreads();
    if (tid == 0) {
#pragma unroll
      for (int w = 0; w < NW; ++w) { s1d += red2[0][w]; s2d += red2[1][w]; }
    }
  }

  if (tid == 0) {
    blkS1[bid] = s1d;                    // ordered by threadfence in bar_arrive
    blkS2[bid] = s2d;
    bar_arrive(bar1, bid);
    bar_wait(bar1, bid);
  }
  __syncthreads();

  // ---------------- phase B: mean/invstd + loss ----------------------------
  // plain loads: ordered after bar_wait's acquire; lines first touched here
  double t1 = 0.0, t2 = 0.0;
  if (tid < NBLK) { t1 = blkS1[tid]; t2 = blkS2[tid]; }
  t1 = wave_sum_d(t1);
  t2 = wave_sum_d(t2);
  if (lane == 0) { red2[0][seg] = t1; red2[1][seg] = t2; }
  __syncthreads();
  if (tid == 0) {
    double S1 = 0.0, S2 = 0.0;
#pragma unroll
    for (int w = 0; w < NW; ++w) { S1 += red2[0][w]; S2 += red2[1][w]; }
    const double dn  = (double)NBLK * RPB * T_DIM;
    const double mean = S1 / dn;
    const double var  = (S2 - S1 * S1 / dn) / (dn - 1.0);
    sc[0] = (float)mean;
    sc[1] = (float)(1.0 / sqrt(var + 1e-8));
  }
  __syncthreads();
  const float meanf = sc[0], invstdf = sc[1];

  float vf_s = 0.f, pg_s = 0.f, n_s = 0.f;
#pragma unroll
  for (int r = 0; r < RPB; ++r) {
    const int  row  = bid * RPB + r;
    const long base = ((long)row * NSEG + seg) * SEG + (long)lane * CH;

    const float4 va0 = *(const float4*)(values + base);
    const float4 va1 = *(const float4*)(values + base + 4);
    const float4 lp0 = *(const float4*)(logprobs + base);
    const float4 lp1 = *(const float4*)(logprobs + base + 4);
    const float4 ol0 = *(const float4*)(old_logprobs + base);
    const float4 ol1 = *(const float4*)(old_logprobs + base + 4);
    const int4   mk0 = *(const int4*)(mask + base);
    const int4   mk1 = *(const int4*)(mask + base + 4);

    float va[CH], lp[CH], ol[CH];
    int mk[CH];
    va[0] = va0.x; va[1] = va0.y; va[2] = va0.z; va[3] = va0.w;
    va[4] = va1.x; va[5] = va1.y; va[6] = va1.z; va[7] = va1.w;
    lp[0] = lp0.x; lp[1] = lp0.y; lp[2] = lp0.z; lp[3] = lp0.w;
    lp[4] = lp1.x; lp[5] = lp1.y; lp[6] = lp1.z; lp[7] = lp1.w;
    ol[0] = ol0.x; ol[1] = ol0.y; ol[2] = ol0.z; ol[3] = ol0.w;
    ol[4] = ol1.x; ol[5] = ol1.y; ol[6] = ol1.z; ol[7] = ol1.w;
    mk[0] = mk0.x; mk[1] = mk0.y; mk[2] = mk0.z; mk[3] = mk0.w;
    mk[4] = mk1.x; mk[5] = mk1.y; mk[6] = mk1.z; mk[7] = mk1.w;

    float cpw = 1.f;
#pragma unroll
    for (int j = CH - 1; j >= 0; --j) {
      cpw *= c;                          // c^(CH-j)
      const float A   = LK[r][j] + carryK[r] * cpw;
      const float mf  = (float)mk[j];
      const float ret = A + vK[r][j];
      const float vc2 = fminf(fmaxf(va[j], vK[r][j] - CLIPV), vK[r][j] + CLIPV);
      const float d1  = va[j] - ret, d2 = vc2 - ret;
      vf_s += fmaxf(d1 * d1, d2 * d2) * mf;
      const float ratio = expf((lp[j] - ol[j]) * mf);
      const float a     = (A - meanf) * invstdf;
      const float p1    = -a * ratio;
      const float p2    = -a * fminf(fmaxf(ratio, 1.f - CLIPR), 1.f + CLIPR);
      pg_s += fmaxf(p1, p2) * mf;
      n_s  += mf;
    }
  }

  double r0 = wave_sum_d((double)vf_s);
  double r1 = wave_sum_d((double)pg_s);
  double r2 = wave_sum_d((double)n_s);
  if (lane == 0) { red3[0][seg] = r0; red3[1][seg] = r1; red3[2][seg] = r2; }
  __syncthreads();
  if (tid == 0) {
    double b0 = 0.0, b1 = 0.0, b2 = 0.0;
#pragma unroll
    for (int w = 0; w < NW; ++w) { b0 += red3[0][w]; b1 += red3[1][w]; b2 += red3[2][w]; }
    part[3 * bid + 0] = b0;              // ordered by threadfence in bar_arrive
    part[3 * bid + 1] = b1;
    part[3 * bid + 2] = b2;
    bar_arrive(bar2, bid);               // arrival only; non-zero blocks exit
  }

  if (bid == 0) {
    if (tid == 0) bar_wait(bar2, bid);
    __syncthreads();
    double vf = 0.0, pg = 0.0, nn = 0.0;
    if (tid < NBLK) {
      vf = part[3 * tid + 0];
      pg = part[3 * tid + 1];
      nn = part[3 * tid + 2];
    }
    vf = wave_sum_d(vf); pg = wave_sum_d(pg); nn = wave_sum_d(nn);
    if (lane == 0) { red3[0][seg] = vf; red3[1][seg] = pg; red3[2][seg] = nn; }
    __syncthreads();
    if (tid == 0) {
      double t0 = 0.0, tp = 0.0, tn = 0.0;
#pragma unroll
      for (int w = 0; w < NW; ++w) {
        t0 += red3[0][w]; tp += red3[1][w]; tn += red3[2][w];
      }
      out[0] = (float)(tp / tn + 0.5 * t0 / tn);   // VF_COEF = 1.0
    }
  }
}

extern "C" void kernel_launch(void* const* d_in, const int* in_sizes, int n_in,
                              void* d_out, int out_size, void* d_ws, size_t ws_size,
                              hipStream_t stream) {
  const float* logprobs     = (const float*)d_in[0];
  const float* values       = (const float*)d_in[1];
  const float* old_logprobs = (const float*)d_in[2];
  const float* old_values   = (const float*)d_in[3];
  const float* rewards      = (const float*)d_in[4];
  const int*   mask         = (const int*)d_in[5];

  char* p = (char*)d_ws;
  int* bar1 = (int*)p;
  int* bar2 = bar1 + BAR_INTS;
  double* blkS1 = (double*)(p + 65536);
  double* blkS2 = blkS1 + NBLK;
  double* part  = blkS2 + NBLK;
  float* outp   = (float*)d_out;

  init_kernel<<<1, 256, 0, stream>>>(bar1);
  coop_kernel<<<NBLK, BT, 0, stream>>>(logprobs, values, old_logprobs,
                                       old_values, rewards, mask, bar1, bar2,
                                       blkS1, blkS2, part, outp);
}

// Round 6
// 41.940 us; speedup vs baseline: 5.4032x; 5.4032x over previous
//
#include <hip/hip_runtime.h>

// PPO model loss — R13: fused kernel; barrier = RELAXED ops + fence-once.
// R12 measurement: 227us (worse than R11's 88). Root cause identified: on
// gfx940+/950, every agent-scope RELEASE store emits buffer_wbl2 (L2
// writeback) and every agent-scope ACQUIRE load emits buffer_inv (cache
// invalidate). R12's 64-release-store broadcast + per-poll acquire loads =
// a cache-maintenance storm (512 waves x 1000s of polls x buffer_inv).
// R13: the idiomatic GPU spin —
//   producer: ONE fence(release,agent), then all-RELAXED tree RMWs +
//             relaxed broadcast flag stores (no wbl2 per store);
//   consumer: RELAXED poll + s_sleep(2), then ONE fence(acquire,agent).
// Also: bar2 dropped entirely — per-block partials via plain stores + the
// R9-proven ~2us finalize kernel (kernel boundary = visibility).
//
//   phase A: 2 rows/block, wave-scan + LDS-compose, row stats ->
//            per-block (s1,s2) doubles; RETAIN v[], L[], carry in registers.
//   bar1   : tree arrival (64 lines x8 -> 8 x8 -> 1) + 64-line relaxed
//            broadcast release; <=8 pollers per flag line.
//   phase B: every block reduces the 512 (s1,s2) pairs -> mean/invstd; loss
//            from RETAINED state + fresh va/lp/ol/mk streams; partial stores.
//   finalize: one block reduces 512 partial triples -> scalar loss.
//
// ws: [0)      144 lines x 32 ints (128B stride) barrier state
//     [32768)  blkS1[512], blkS2[512], part[3*512] doubles

static constexpr int T_DIM = 4096;
static constexpr int SEG   = 512;          // elements per segment (one wave)
static constexpr int NSEG  = 8;            // segments per row
static constexpr int CH    = 8;            // elements per lane
static constexpr int BT    = 512;          // 8 waves per block
static constexpr int NW    = 8;
static constexpr int RPB   = 2;            // rows per block
static constexpr int NBLK  = 512;          // grid = nrows / RPB  (nrows=1024)

#define CDEC 0.95f
#define CLIPR 0.2f
#define CLIPV 0.2f
#define AGENT __HIP_MEMORY_SCOPE_AGENT

// ------- barrier state: 144 lines x 32 ints (counters 0..72, flags 80..143)
static constexpr int LSTRIDE  = 32;             // 128 B between lines
static constexpr int BAR_INTS = 144 * LSTRIDE;

__device__ __forceinline__ void bar_arrive(int* base, int bid) {
  // thread 0 of each block; caller's global stores must precede
  __builtin_amdgcn_fence(__ATOMIC_RELEASE, "agent");   // ONE wbl2
  const int line0 = bid & 63;
  if (__hip_atomic_fetch_add(base + line0 * LSTRIDE, 1,
                             __ATOMIC_RELAXED, AGENT) == (NBLK >> 6) - 1) {
    if (__hip_atomic_fetch_add(base + (64 + (line0 >> 3)) * LSTRIDE, 1,
                               __ATOMIC_RELAXED, AGENT) == 7) {
      if (__hip_atomic_fetch_add(base + 72 * LSTRIDE, 1,
                                 __ATOMIC_RELAXED, AGENT) == 7) {
        // relaxed broadcast: 64 flag lines, <=8 pollers each, no wbl2
#pragma unroll
        for (int i = 0; i < 64; ++i)
          __hip_atomic_store(base + (80 + i) * LSTRIDE, 1,
                             __ATOMIC_RELAXED, AGENT);
      }
    }
  }
}
__device__ __forceinline__ void bar_wait(int* base, int bid) {
  int* flag = base + (80 + (bid & 63)) * LSTRIDE;
  while (__hip_atomic_load(flag, __ATOMIC_RELAXED, AGENT) == 0)
    __builtin_amdgcn_s_sleep(2);
  __builtin_amdgcn_fence(__ATOMIC_ACQUIRE, "agent");   // ONE buffer_inv
}

__device__ __forceinline__ double wave_sum_d(double v) {
#pragma unroll
  for (int d = 32; d > 0; d >>= 1) v += __shfl_down(v, d);
  return v;
}
// inclusive suffix scan of affine (L, M) across the 64-lane wave
__device__ __forceinline__ void wave_suffix(float& sL, float& sM, int lane) {
#pragma unroll
  for (int d = 1; d < 64; d <<= 1) {
    float oL = __shfl_down(sL, d);
    float oM = __shfl_down(sM, d);
    if (lane + d < 64) { sL += sM * oL; sM *= oM; }
  }
}

// ---------------- init: zero barrier state ---------------------------------
__global__ __launch_bounds__(256) void init_kernel(int* bar) {
  for (int i = threadIdx.x; i < BAR_INTS; i += 256) bar[i] = 0;
}

// ---------------- fused kernel (plain launch, capacity-guaranteed) ---------
__global__ __launch_bounds__(BT, 4) void coop_kernel(
    const float* __restrict__ logprobs,
    const float* __restrict__ values,
    const float* __restrict__ old_logprobs,
    const float* __restrict__ old_values,
    const float* __restrict__ rewards,
    const int*   __restrict__ mask,
    int* __restrict__ bar1,
    double* __restrict__ blkS1, double* __restrict__ blkS2,
    double* __restrict__ part) {
  const int tid  = threadIdx.x;
  const int lane = tid & 63;
  const int seg  = tid >> 6;          // wave id == segment id within row
  const int bid  = blockIdx.x;
  const float c  = CDEC;

  __shared__ float  segL[NSEG], segM[NSEG], segC[NSEG];
  __shared__ double red2[2][NW];
  __shared__ double red3[3][NW];
  __shared__ float  sc[2];

  float cCH;
  { float pw = 1.f;
#pragma unroll
    for (int i = 0; i < CH; ++i) pw *= c;
    cCH = pw; }

  // ---------------- phase A: row stats, retain scan state ------------------
  float vK[RPB][CH], LK[RPB][CH], carryK[RPB];
  double s1d = 0.0, s2d = 0.0;

#pragma unroll
  for (int r = 0; r < RPB; ++r) {
    const int  row  = bid * RPB + r;
    const long base = ((long)row * NSEG + seg) * SEG + (long)lane * CH;

    const float4 rv0 = *(const float4*)(rewards + base);
    const float4 rv1 = *(const float4*)(rewards + base + 4);
    const float4 vv0 = *(const float4*)(old_values + base);
    const float4 vv1 = *(const float4*)(old_values + base + 4);

    float v9[CH + 1], rw[CH];
    v9[0] = vv0.x; v9[1] = vv0.y; v9[2] = vv0.z; v9[3] = vv0.w;
    v9[4] = vv1.x; v9[5] = vv1.y; v9[6] = vv1.z; v9[7] = vv1.w;
    rw[0] = rv0.x; rw[1] = rv0.y; rw[2] = rv0.z; rw[3] = rv0.w;
    rw[4] = rv1.x; rw[5] = rv1.y; rw[6] = rv1.z; rw[7] = rv1.w;
    float nv = __shfl_down(v9[0], 1);
    if (lane == 63) nv = (seg == NSEG - 1) ? 0.f : old_values[base + CH];
    v9[CH] = nv;

    // local suffix scan (zero carry-in)
    LK[r][CH - 1] = rw[CH - 1] + v9[CH] - v9[CH - 1];
#pragma unroll
    for (int j = CH - 2; j >= 0; --j)
      LK[r][j] = (rw[j] + v9[j + 1] - v9[j]) + c * LK[r][j + 1];
#pragma unroll
    for (int j = 0; j < CH; ++j) vK[r][j] = v9[j];

    float sL = LK[r][0], sM = cCH;
    wave_suffix(sL, sM, lane);
    float nLc = __shfl_down(sL, 1);
    float nMc = __shfl_down(sM, 1);
    if (lane == 63) { nLc = 0.f; nMc = 1.f; }

    if (lane == 0) { segL[seg] = sL; segM[seg] = sM; }
    __syncthreads();
    if (tid == 0) {
      float C = 0.f;
#pragma unroll
      for (int s = NSEG - 1; s >= 0; --s) { segC[s] = C; C = segL[s] + segM[s] * C; }
    }
    __syncthreads();
    carryK[r] = nLc + nMc * segC[seg];

    float s1 = 0.f, s2 = 0.f;
    { float cpw = 1.f;
#pragma unroll
      for (int j = CH - 1; j >= 0; --j) {
        cpw *= c;                        // c^(CH-j)
        const float A = LK[r][j] + carryK[r] * cpw;
        s1 += A; s2 += A * A;
      } }

    double d1 = wave_sum_d((double)s1);
    double d2 = wave_sum_d((double)s2);
    if (lane == 0) { red2[0][seg] = d1; red2[1][seg] = d2; }
    __syncthreads();
    if (tid == 0) {
#pragma unroll
      for (int w = 0; w < NW; ++w) { s1d += red2[0][w]; s2d += red2[1][w]; }
    }
  }

  if (tid == 0) {
    blkS1[bid] = s1d;                    // ordered by release fence in arrive
    blkS2[bid] = s2d;
    bar_arrive(bar1, bid);
    bar_wait(bar1, bid);
  }
  __syncthreads();

  // ---------------- phase B: mean/invstd + loss ----------------------------
  // plain loads: ordered after bar_wait's acquire fence + syncthreads
  double t1 = 0.0, t2 = 0.0;
  if (tid < NBLK) { t1 = blkS1[tid]; t2 = blkS2[tid]; }
  t1 = wave_sum_d(t1);
  t2 = wave_sum_d(t2);
  if (lane == 0) { red2[0][seg] = t1; red2[1][seg] = t2; }
  __syncthreads();
  if (tid == 0) {
    double S1 = 0.0, S2 = 0.0;
#pragma unroll
    for (int w = 0; w < NW; ++w) { S1 += red2[0][w]; S2 += red2[1][w]; }
    const double dn  = (double)NBLK * RPB * T_DIM;
    const double mean = S1 / dn;
    const double var  = (S2 - S1 * S1 / dn) / (dn - 1.0);
    sc[0] = (float)mean;
    sc[1] = (float)(1.0 / sqrt(var + 1e-8));
  }
  __syncthreads();
  const float meanf = sc[0], invstdf = sc[1];

  float vf_s = 0.f, pg_s = 0.f, n_s = 0.f;
#pragma unroll
  for (int r = 0; r < RPB; ++r) {
    const int  row  = bid * RPB + r;
    const long base = ((long)row * NSEG + seg) * SEG + (long)lane * CH;

    const float4 va0 = *(const float4*)(values + base);
    const float4 va1 = *(const float4*)(values + base + 4);
    const float4 lp0 = *(const float4*)(logprobs + base);
    const float4 lp1 = *(const float4*)(logprobs + base + 4);
    const float4 ol0 = *(const float4*)(old_logprobs + base);
    const float4 ol1 = *(const float4*)(old_logprobs + base + 4);
    const int4   mk0 = *(const int4*)(mask + base);
    const int4   mk1 = *(const int4*)(mask + base + 4);

    float va[CH], lp[CH], ol[CH];
    int mk[CH];
    va[0] = va0.x; va[1] = va0.y; va[2] = va0.z; va[3] = va0.w;
    va[4] = va1.x; va[5] = va1.y; va[6] = va1.z; va[7] = va1.w;
    lp[0] = lp0.x; lp[1] = lp0.y; lp[2] = lp0.z; lp[3] = lp0.w;
    lp[4] = lp1.x; lp[5] = lp1.y; lp[6] = lp1.z; lp[7] = lp1.w;
    ol[0] = ol0.x; ol[1] = ol0.y; ol[2] = ol0.z; ol[3] = ol0.w;
    ol[4] = ol1.x; ol[5] = ol1.y; ol[6] = ol1.z; ol[7] = ol1.w;
    mk[0] = mk0.x; mk[1] = mk0.y; mk[2] = mk0.z; mk[3] = mk0.w;
    mk[4] = mk1.x; mk[5] = mk1.y; mk[6] = mk1.z; mk[7] = mk1.w;

    float cpw = 1.f;
#pragma unroll
    for (int j = CH - 1; j >= 0; --j) {
      cpw *= c;                          // c^(CH-j)
      const float A   = LK[r][j] + carryK[r] * cpw;
      const float mf  = (float)mk[j];
      const float ret = A + vK[r][j];
      const float vc2 = fminf(fmaxf(va[j], vK[r][j] - CLIPV), vK[r][j] + CLIPV);
      const float d1  = va[j] - ret, d2 = vc2 - ret;
      vf_s += fmaxf(d1 * d1, d2 * d2) * mf;
      const float ratio = expf((lp[j] - ol[j]) * mf);
      const float a     = (A - meanf) * invstdf;
      const float p1    = -a * ratio;
      const float p2    = -a * fminf(fmaxf(ratio, 1.f - CLIPR), 1.f + CLIPR);
      pg_s += fmaxf(p1, p2) * mf;
      n_s  += mf;
    }
  }

  double r0 = wave_sum_d((double)vf_s);
  double r1 = wave_sum_d((double)pg_s);
  double r2 = wave_sum_d((double)n_s);
  if (lane == 0) { red3[0][seg] = r0; red3[1][seg] = r1; red3[2][seg] = r2; }
  __syncthreads();
  if (tid == 0) {
    double b0 = 0.0, b1 = 0.0, b2 = 0.0;
#pragma unroll
    for (int w = 0; w < NW; ++w) { b0 += red3[0][w]; b1 += red3[1][w]; b2 += red3[2][w]; }
    part[3 * bid + 0] = b0;              // plain stores; kernel boundary
    part[3 * bid + 1] = b1;              // guarantees visibility to finalize
    part[3 * bid + 2] = b2;
  }
}

// ---------------- finalize: reduce per-block partials ----------------------
__global__ __launch_bounds__(1024) void finalize_kernel(
    const double* __restrict__ part, int nblk, float* __restrict__ out) {
  const int tid  = threadIdx.x;
  const int lane = tid & 63;
  const int wave = tid >> 6;
  double vf = 0.0, pg = 0.0, n = 0.0;
  for (int i = tid; i < nblk; i += 1024) {
    vf += part[3 * i + 0];
    pg += part[3 * i + 1];
    n  += part[3 * i + 2];
  }
  __shared__ double red[3][16];
  vf = wave_sum_d(vf); pg = wave_sum_d(pg); n = wave_sum_d(n);
  if (lane == 0) { red[0][wave] = vf; red[1][wave] = pg; red[2][wave] = n; }
  __syncthreads();
  if (tid == 0) {
    double t0 = 0.0, t1 = 0.0, t2 = 0.0;
#pragma unroll
    for (int w = 0; w < 16; ++w) {
      t0 += red[0][w]; t1 += red[1][w]; t2 += red[2][w];
    }
    out[0] = (float)(t1 / t2 + 0.5 * t0 / t2);   // VF_COEF = 1.0
  }
}

extern "C" void kernel_launch(void* const* d_in, const int* in_sizes, int n_in,
                              void* d_out, int out_size, void* d_ws, size_t ws_size,
                              hipStream_t stream) {
  const float* logprobs     = (const float*)d_in[0];
  const float* values       = (const float*)d_in[1];
  const float* old_logprobs = (const float*)d_in[2];
  const float* old_values   = (const float*)d_in[3];
  const float* rewards      = (const float*)d_in[4];
  const int*   mask         = (const int*)d_in[5];

  char* p = (char*)d_ws;
  int* bar1 = (int*)p;
  double* blkS1 = (double*)(p + 32768);
  double* blkS2 = blkS1 + NBLK;
  double* part  = blkS2 + NBLK;
  float* outp   = (float*)d_out;

  init_kernel<<<1, 256, 0, stream>>>(bar1);
  coop_kernel<<<NBLK, BT, 0, stream>>>(logprobs, values, old_logprobs,
                                       old_values, rewards, mask, bar1,
                                       blkS1, blkS2, part);
  finalize_kernel<<<1, 1024, 0, stream>>>(part, NBLK, outp);
}